// Round 12
// baseline (135.013 us; speedup 1.0000x reference)
//
#include <hip/hip_runtime.h>
#include <hip/hip_bf16.h>

#define D_FEAT 128
#define D4 (D_FEAT / 4)
#define BKT_SHIFT 7            // 128 nodes per bucket
#define BKT_NODES 128
#define NCHUNK 256             // edge chunks (partition blocks)
#define MAXBKT 512
#define SLOT 5120              // static per-bucket slots == LDS sort capacity
#define KA_R 8                 // max rounds/thread in ka -> E <= 256*512*8

__device__ inline unsigned pack_bf2(float lo, float hi) {
    __hip_bfloat162 h = __float22bfloat162_rn(make_float2(lo, hi));
    unsigned u;
    __builtin_memcpy((void*)&u, (const void*)&h, 4);
    return u;
}

__device__ inline float2 bf2_to_f2(unsigned u) {
    __hip_bfloat162 h;
    __builtin_memcpy((void*)&h, (const void*)&u, 4);
    return __bfloat1622float2(h);
}

// ---- KA: blocks < NCHUNK: SINGLE-PASS partition. Each thread loads its
//      <=KA_R edges once (coalesced; nontemporal on the scalar streams),
//      hists from registers, reserves per-bucket ranges with one global
//      atomic per (block,bucket), scatters from registers (~64B runs).
//      Blocks >= NCHUNK: fp32 -> bf16 feature cvt (uint4 16B stores).
__global__ __launch_bounds__(512) void ka_part_cvt(
        const int* __restrict__ src, const int* __restrict__ dst,
        const float* __restrict__ vals, int E, int chunk, int nbkt,
        int* __restrict__ gcur, int* __restrict__ ovcnt, int4* __restrict__ ov,
        int2* __restrict__ spackA,
        const float4* __restrict__ fin4, uint4* __restrict__ fb4, int n8) {
    int c = blockIdx.x;
    int tid = threadIdx.x;
    if (c < NCHUNK) {
        __shared__ int hist[MAXBKT];
        __shared__ int lcur[MAXBKT];
        for (int i = tid; i < nbkt; i += 512) hist[i] = 0;
        __syncthreads();
        int lo = c * chunk;
        int hi = min(lo + chunk, E);
        int d[KA_R], sr[KA_R];
        float vv[KA_R];
#pragma unroll
        for (int r = 0; r < KA_R; ++r) {
            int i = lo + r * 512 + tid;
            if (i < hi) {
                d[r]  = __builtin_nontemporal_load(&dst[i]);
                sr[r] = __builtin_nontemporal_load(&src[i]);
                vv[r] = __builtin_nontemporal_load(&vals[i]);
                atomicAdd(&hist[d[r] >> BKT_SHIFT], 1);
            }
        }
        __syncthreads();
        for (int i = tid; i < nbkt; i += 512) {
            int h = hist[i];
            lcur[i] = h ? (i * SLOT + atomicAdd(&gcur[i], h)) : 0;
        }
        __syncthreads();
#pragma unroll
        for (int r = 0; r < KA_R; ++r) {
            int i = lo + r * 512 + tid;
            if (i < hi) {
                int bkt = d[r] >> BKT_SHIFT;
                int pos = atomicAdd(&lcur[bkt], 1);
                if (pos - bkt * SLOT < SLOT) {
                    spackA[pos] = make_int2((sr[r] & 0xFFFF) |
                                            ((d[r] & (BKT_NODES - 1)) << 16),
                                            __float_as_int(vv[r]));
                } else {
                    int oi = atomicAdd(ovcnt, 1);
                    ov[oi] = make_int4(sr[r], d[r], __float_as_int(vv[r]), 0);
                }
            }
        }
    } else {
        int nb = gridDim.x - NCHUNK;
        int idx = (c - NCHUNK) * 512 + tid;
        int stride = nb * 512;
        for (int i = idx; i < n8; i += stride) {   // one uint4 (8 bf16) each
            float4 a = fin4[2 * i + 0];
            float4 b = fin4[2 * i + 1];
            uint4 o;
            o.x = pack_bf2(a.x, a.y);
            o.y = pack_bf2(a.z, a.w);
            o.z = pack_bf2(b.x, b.y);
            o.w = pack_bf2(b.z, b.w);
            fb4[i] = o;
        }
    }
}

// ---- KB: PERSISTENT work-stealing blocks (2/CU, fully resident). Each block
//      grabs bucket ids from a global queue, runs the single-pass counting
//      sort (spackA as int4, register-resident) INTO LDS + quad gather
//      (16 lanes/edge x uint4 16B), shfl_xor cross-quarter reduce.
//      Work-stealing removes the 76% CU-quantization ceiling of the
//      one-block-per-bucket launch.
__global__ __launch_bounds__(1024) void kb_sort_gather(
        const int* __restrict__ gcur, const int2* __restrict__ spackA,
        const uint4* __restrict__ feat4u,
        const float4* __restrict__ bias4, float4* __restrict__ out4,
        int N, int nbkt, int* __restrict__ wq) {
    __shared__ int hist[BKT_NODES];
    __shared__ int sbuf[BKT_NODES];   // inclusive scan (kept for gather)
    __shared__ int lcur[BKT_NODES];
    __shared__ int sh_b;
    __shared__ int2 ls[SLOT];
    int tid = threadIdx.x;
    int wave = tid >> 6, lane = tid & 63;
    int q  = lane >> 4;             // edge slot within group-of-4
    int ql = lane & 15;             // feature chunk: feats 8ql..8ql+7
    float4 bvA = bias4[2 * ql];
    float4 bvB = bias4[2 * ql + 1];

    for (;;) {
        if (tid == 0) sh_b = atomicAdd(wq, 1);
        __syncthreads();
        int b = sh_b;
        if (b >= nbkt) return;

        int cnt = gcur[b];
        if (cnt > SLOT) cnt = SLOT;
        int base = b * SLOT;
        const int4* sp4 = (const int4*)(spackA + base);  // 16B-aligned

        if (tid < BKT_NODES) hist[tid] = 0;
        __syncthreads();
        int4 w[3];                    // 3 rounds x 2 packets = 6 packets max
#pragma unroll
        for (int r = 0; r < 3; ++r) {
            int i = (r << 11) + (tid << 1);
            if (i < cnt) {
                w[r] = sp4[(r << 10) + tid];
                atomicAdd(&hist[(w[r].x >> 16) & (BKT_NODES - 1)], 1);
                if (i + 1 < cnt)
                    atomicAdd(&hist[(w[r].z >> 16) & (BKT_NODES - 1)], 1);
            }
        }
        __syncthreads();
        // single-wave scan of the 128-entry histogram (2/lane, shfl)
        if (tid < 64) {
            int h0 = hist[2 * tid], h1 = hist[2 * tid + 1];
            int s = h0 + h1;
            int v = s;
            for (int off = 1; off < 64; off <<= 1) {
                int t = __shfl_up(v, off, 64);
                if (tid >= off) v += t;
            }
            sbuf[2 * tid]     = v - h1;   // inclusive at 2l
            sbuf[2 * tid + 1] = v;        // inclusive at 2l+1
            lcur[2 * tid]     = v - s;    // exclusive
            lcur[2 * tid + 1] = v - h1;
        }
        __syncthreads();
#pragma unroll
        for (int r = 0; r < 3; ++r) {
            int i = (r << 11) + (tid << 1);
            if (i < cnt) {
                int p = atomicAdd(&lcur[(w[r].x >> 16) & (BKT_NODES - 1)], 1);
                ls[p] = make_int2(w[r].x, w[r].y);
                if (i + 1 < cnt) {
                    int p2 = atomicAdd(&lcur[(w[r].z >> 16) & (BKT_NODES - 1)], 1);
                    ls[p2] = make_int2(w[r].z, w[r].w);
                }
            }
        }
        __syncthreads();

        for (int n = wave; n < BKT_NODES; n += 16) {
            int node = (b << BKT_SHIFT) + n;
            if (node >= N) break;
            int lend = sbuf[n];
            int lbeg = lend - hist[n];
            float4 aA = make_float4(0.f, 0.f, 0.f, 0.f);
            float4 aB = make_float4(0.f, 0.f, 0.f, 0.f);
            for (int e0 = lbeg; e0 < lend; e0 += 16) {
                int2 p[4];
                uint4 h[4];
#pragma unroll
                for (int j = 0; j < 4; j++)
                    p[j] = ls[min(e0 + 4 * j + q, lend - 1)];
#pragma unroll
                for (int j = 0; j < 4; j++)
                    h[j] = feat4u[(size_t)(p[j].x & 0xFFFF) * 16 + ql];
#pragma unroll
                for (int j = 0; j < 4; j++) {
                    float v = (e0 + 4 * j + q < lend) ?
                              __int_as_float(p[j].y) : 0.f;
                    float2 f0 = bf2_to_f2(h[j].x);
                    float2 f1 = bf2_to_f2(h[j].y);
                    float2 f2 = bf2_to_f2(h[j].z);
                    float2 f3 = bf2_to_f2(h[j].w);
                    aA.x += v * f0.x; aA.y += v * f0.y;
                    aA.z += v * f1.x; aA.w += v * f1.y;
                    aB.x += v * f2.x; aB.y += v * f2.y;
                    aB.z += v * f3.x; aB.w += v * f3.y;
                }
            }
            // reduce across the 4 edge-quarters
#pragma unroll
            for (int m = 16; m <= 32; m <<= 1) {
                aA.x += __shfl_xor(aA.x, m); aA.y += __shfl_xor(aA.y, m);
                aA.z += __shfl_xor(aA.z, m); aA.w += __shfl_xor(aA.w, m);
                aB.x += __shfl_xor(aB.x, m); aB.y += __shfl_xor(aB.y, m);
                aB.z += __shfl_xor(aB.z, m); aB.w += __shfl_xor(aB.w, m);
            }
            if (q == 0) {
                out4[(size_t)node * 32 + 2 * ql] =
                    make_float4(aA.x + bvA.x, aA.y + bvA.y,
                                aA.z + bvA.z, aA.w + bvA.w);
                out4[(size_t)node * 32 + 2 * ql + 1] =
                    make_float4(aB.x + bvB.x, aB.y + bvB.y,
                                aB.z + bvB.z, aB.w + bvB.w);
            }
        }
        __syncthreads();   // protect hist/ls before next bucket's zeroing
    }
}

// ---- K_over: drain overflow edges (adversarial skew only; exits instantly
//      when ovcnt == 0). Global float atomics over fp32 features.
__global__ __launch_bounds__(256) void k_over(
        const int4* __restrict__ ov, const int* __restrict__ ovcnt,
        const float4* __restrict__ feat4, float* __restrict__ out) {
    int total = *ovcnt;
    long long items = (long long)total * 32;
    long long stride = (long long)gridDim.x * blockDim.x;
    for (long long i = (long long)blockIdx.x * blockDim.x + threadIdx.x;
         i < items; i += stride) {
        int e = (int)(i >> 5);
        int lane = (int)(i & 31);
        int4 r = ov[e];
        float v = __int_as_float(r.z);
        float4 f = feat4[(size_t)r.x * 32 + lane];
        float* o = out + (size_t)r.y * D_FEAT + lane * 4;
        atomicAdd(o + 0, v * f.x);
        atomicAdd(o + 1, v * f.y);
        atomicAdd(o + 2, v * f.z);
        atomicAdd(o + 3, v * f.w);
    }
}

// ---------- last-resort atomic path ----------

__global__ void init_bias_kernel(float4* __restrict__ out,
                                 const float4* __restrict__ bias, int n4) {
    int i = blockIdx.x * blockDim.x + threadIdx.x;
    if (i < n4) out[i] = bias[i & (D4 - 1)];
}

__global__ void spmm_edge_kernel(const int* __restrict__ src,
                                 const int* __restrict__ dst,
                                 const float* __restrict__ vals,
                                 const float4* __restrict__ feat,
                                 float* __restrict__ out, int n_edges) {
    int tid = blockIdx.x * blockDim.x + threadIdx.x;
    int e = tid >> 5;
    int lane = tid & 31;
    if (e >= n_edges) return;
    int s = src[e];
    int d = dst[e];
    float v = vals[e];
    float4 f = feat[(size_t)s * D4 + lane];
    float* o = out + (size_t)d * D_FEAT + lane * 4;
    atomicAdd(o + 0, v * f.x);
    atomicAdd(o + 1, v * f.y);
    atomicAdd(o + 2, v * f.z);
    atomicAdd(o + 3, v * f.w);
}

extern "C" void kernel_launch(void* const* d_in, const int* in_sizes, int n_in,
                              void* d_out, int out_size, void* d_ws, size_t ws_size,
                              hipStream_t stream) {
    const int* edge_index = (const int*)d_in[0];    // (2, E) int32
    const float* edge_vals = (const float*)d_in[1]; // (E,)
    const float* features  = (const float*)d_in[2]; // (N, 128)
    const float* bias      = (const float*)d_in[3]; // (128,)

    int E = in_sizes[1];
    int N = in_sizes[2] / D_FEAT;
    const int* src = edge_index;
    const int* dst = edge_index + E;
    float* out = (float*)d_out;

    int nbkt = (N + BKT_NODES - 1) >> BKT_SHIFT;
    int n8 = N * D_FEAT / 8;        // uint4 units in the bf16 table
    int chunk = (E + NCHUNK - 1) / NCHUNK;

    // ws: fb16 | spackA[nbkt*SLOT] | ov[E] | gcur[MAXBKT] | ovcnt | wq
    size_t fb_bytes = (size_t)N * D_FEAT * 2;
    size_t spA_bytes = (size_t)nbkt * SLOT * 8;
    size_t ov_bytes = (size_t)E * 16;
    size_t needed = fb_bytes + spA_bytes + ov_bytes + ((size_t)MAXBKT + 2) * 4;

    bool ok = (ws_size >= needed) && (N >= 1) && (N <= 65536) && (E >= 1) &&
              (E <= NCHUNK * 512 * KA_R) && (in_sizes[3] == D_FEAT) &&
              (nbkt <= MAXBKT);

    if (ok) {
        char* wp = (char*)d_ws;
        uint4* fb16 = (uint4*)wp;                      wp += fb_bytes;
        int2* spackA = (int2*)wp;                      wp += spA_bytes;
        int4* ov     = (int4*)wp;                      wp += ov_bytes;
        int* gcur    = (int*)wp;
        int* ovcnt   = gcur + MAXBKT;
        int* wq      = gcur + MAXBKT + 1;

        (void)hipMemsetAsync(gcur, 0, ((size_t)MAXBKT + 2) * 4, stream);

        ka_part_cvt<<<NCHUNK + 256, 512, 0, stream>>>(
            src, dst, edge_vals, E, chunk, nbkt,
            gcur, ovcnt, ov, spackA,
            (const float4*)features, fb16, n8);
        int gb = nbkt < 512 ? nbkt : 512;
        kb_sort_gather<<<gb, 1024, 0, stream>>>(
            gcur, spackA, (const uint4*)fb16,
            (const float4*)bias, (float4*)out, N, nbkt, wq);
        k_over<<<32, 256, 0, stream>>>(ov, ovcnt,
                                       (const float4*)features, out);
    } else {
        int no4 = out_size / 4;
        {
            int block = 256, grid = (no4 + block - 1) / block;
            init_bias_kernel<<<grid, block, 0, stream>>>((float4*)out,
                                                         (const float4*)bias, no4);
        }
        {
            int block = 256;
            long long total = (long long)E * 32;
            int grid = (int)((total + block - 1) / block);
            spmm_edge_kernel<<<grid, block, 0, stream>>>(src, dst, edge_vals,
                                                         (const float4*)features,
                                                         out, E);
        }
    }
}

// Round 13
// 128.987 us; speedup vs baseline: 1.0467x; 1.0467x over previous
//
#include <hip/hip_runtime.h>
#include <hip/hip_bf16.h>

#define D_FEAT 128
#define D4 (D_FEAT / 4)
#define BKT_SHIFT 7            // 128 nodes per bucket
#define BKT_NODES 128
#define NCHUNK 256             // edge chunks (partition blocks)
#define MAXBKT 512
#define SLOT 5120              // static per-bucket slots == LDS sort capacity
#define KA_R 8                 // max rounds/thread in ka -> E <= 256*512*8

__device__ inline unsigned pack_bf2(float lo, float hi) {
    __hip_bfloat162 h = __float22bfloat162_rn(make_float2(lo, hi));
    unsigned u;
    __builtin_memcpy((void*)&u, (const void*)&h, 4);
    return u;
}

__device__ inline float2 bf2_to_f2(unsigned u) {
    __hip_bfloat162 h;
    __builtin_memcpy((void*)&h, (const void*)&u, 4);
    return __bfloat1622float2(h);
}

// ---- KA: blocks < NCHUNK: SINGLE-PASS partition. Each thread loads its
//      <=KA_R edges once (coalesced; nontemporal on the scalar streams),
//      hists from registers, reserves per-bucket ranges with one global
//      atomic per (block,bucket), scatters from registers (~64B runs).
//      Blocks >= NCHUNK: fp32 -> bf16 feature cvt (uint4 16B stores).
__global__ __launch_bounds__(512) void ka_part_cvt(
        const int* __restrict__ src, const int* __restrict__ dst,
        const float* __restrict__ vals, int E, int chunk, int nbkt,
        int* __restrict__ gcur, int* __restrict__ ovcnt, int4* __restrict__ ov,
        int2* __restrict__ spackA,
        const float4* __restrict__ fin4, uint4* __restrict__ fb4, int n8) {
    int c = blockIdx.x;
    int tid = threadIdx.x;
    if (c < NCHUNK) {
        __shared__ int hist[MAXBKT];
        __shared__ int lcur[MAXBKT];
        for (int i = tid; i < nbkt; i += 512) hist[i] = 0;
        __syncthreads();
        int lo = c * chunk;
        int hi = min(lo + chunk, E);
        int d[KA_R], sr[KA_R];
        float vv[KA_R];
#pragma unroll
        for (int r = 0; r < KA_R; ++r) {
            int i = lo + r * 512 + tid;
            if (i < hi) {
                d[r]  = __builtin_nontemporal_load(&dst[i]);
                sr[r] = __builtin_nontemporal_load(&src[i]);
                vv[r] = __builtin_nontemporal_load(&vals[i]);
                atomicAdd(&hist[d[r] >> BKT_SHIFT], 1);
            }
        }
        __syncthreads();
        for (int i = tid; i < nbkt; i += 512) {
            int h = hist[i];
            lcur[i] = h ? (i * SLOT + atomicAdd(&gcur[i], h)) : 0;
        }
        __syncthreads();
#pragma unroll
        for (int r = 0; r < KA_R; ++r) {
            int i = lo + r * 512 + tid;
            if (i < hi) {
                int bkt = d[r] >> BKT_SHIFT;
                int pos = atomicAdd(&lcur[bkt], 1);
                if (pos - bkt * SLOT < SLOT) {
                    spackA[pos] = make_int2((sr[r] & 0xFFFF) |
                                            ((d[r] & (BKT_NODES - 1)) << 16),
                                            __float_as_int(vv[r]));
                } else {
                    int oi = atomicAdd(ovcnt, 1);
                    ov[oi] = make_int4(sr[r], d[r], __float_as_int(vv[r]), 0);
                }
            }
        }
    } else {
        int nb = gridDim.x - NCHUNK;
        int idx = (c - NCHUNK) * 512 + tid;
        int stride = nb * 512;
        for (int i = idx; i < n8; i += stride) {   // one uint4 (8 bf16) each
            float4 a = fin4[2 * i + 0];
            float4 b = fin4[2 * i + 1];
            uint4 o;
            o.x = pack_bf2(a.x, a.y);
            o.y = pack_bf2(a.z, a.w);
            o.z = pack_bf2(b.x, b.y);
            o.w = pack_bf2(b.z, b.w);
            fb4[i] = o;
        }
    }
}

// ---- KB: SINGLE-PASS per-bucket counting sort (spackA read once as int4,
//      2 packets/lane, register-resident) INTO LDS + quad gather
//      (16 lanes/edge x uint4 16B). Cross-quarter reduce via shfl_xor.
__global__ __launch_bounds__(1024) void kb_sort_gather(
        const int* __restrict__ gcur, const int2* __restrict__ spackA,
        const uint4* __restrict__ feat4u,
        const float4* __restrict__ bias4, float4* __restrict__ out4, int N) {
    __shared__ int hist[BKT_NODES];
    __shared__ int sbuf[BKT_NODES];   // inclusive scan (kept for gather)
    __shared__ int lcur[BKT_NODES];
    __shared__ int2 ls[SLOT];
    int b = blockIdx.x;
    int tid = threadIdx.x;
    int cnt = gcur[b];
    if (cnt > SLOT) cnt = SLOT;
    int base = b * SLOT;
    const int4* sp4 = (const int4*)(spackA + base);   // 16B-aligned (SLOT even)

    if (tid < BKT_NODES) hist[tid] = 0;
    __syncthreads();
    int4 w[3];                        // 3 rounds x 2 packets = 6 packets max
#pragma unroll
    for (int r = 0; r < 3; ++r) {
        int i = (r << 11) + (tid << 1);
        if (i < cnt) {
            w[r] = sp4[(r << 10) + tid];
            atomicAdd(&hist[(w[r].x >> 16) & (BKT_NODES - 1)], 1);
            if (i + 1 < cnt)
                atomicAdd(&hist[(w[r].z >> 16) & (BKT_NODES - 1)], 1);
        }
    }
    __syncthreads();
    // single-wave scan of the 128-entry histogram (2/lane, shfl)
    if (tid < 64) {
        int h0 = hist[2 * tid], h1 = hist[2 * tid + 1];
        int s = h0 + h1;
        int v = s;
        for (int off = 1; off < 64; off <<= 1) {
            int t = __shfl_up(v, off, 64);
            if (tid >= off) v += t;
        }
        sbuf[2 * tid]     = v - h1;   // inclusive at 2l
        sbuf[2 * tid + 1] = v;        // inclusive at 2l+1
        lcur[2 * tid]     = v - s;    // exclusive
        lcur[2 * tid + 1] = v - h1;
    }
    __syncthreads();
#pragma unroll
    for (int r = 0; r < 3; ++r) {
        int i = (r << 11) + (tid << 1);
        if (i < cnt) {
            int p = atomicAdd(&lcur[(w[r].x >> 16) & (BKT_NODES - 1)], 1);
            ls[p] = make_int2(w[r].x, w[r].y);
            if (i + 1 < cnt) {
                int p2 = atomicAdd(&lcur[(w[r].z >> 16) & (BKT_NODES - 1)], 1);
                ls[p2] = make_int2(w[r].z, w[r].w);
            }
        }
    }
    __syncthreads();

    int wave = tid >> 6, lane = tid & 63;
    int q  = lane >> 4;             // edge slot within group-of-4
    int ql = lane & 15;             // feature chunk: feats 8ql..8ql+7
    float4 bvA = bias4[2 * ql];
    float4 bvB = bias4[2 * ql + 1];
    for (int n = wave; n < BKT_NODES; n += 16) {
        int node = (b << BKT_SHIFT) + n;
        if (node >= N) break;
        int lend = sbuf[n];
        int lbeg = lend - hist[n];
        float4 aA = make_float4(0.f, 0.f, 0.f, 0.f);
        float4 aB = make_float4(0.f, 0.f, 0.f, 0.f);
        for (int e0 = lbeg; e0 < lend; e0 += 16) {
            int2 p[4];
            uint4 h[4];
#pragma unroll
            for (int j = 0; j < 4; j++)
                p[j] = ls[min(e0 + 4 * j + q, lend - 1)];
#pragma unroll
            for (int j = 0; j < 4; j++)
                h[j] = feat4u[(size_t)(p[j].x & 0xFFFF) * 16 + ql];
#pragma unroll
            for (int j = 0; j < 4; j++) {
                float v = (e0 + 4 * j + q < lend) ?
                          __int_as_float(p[j].y) : 0.f;
                float2 f0 = bf2_to_f2(h[j].x);
                float2 f1 = bf2_to_f2(h[j].y);
                float2 f2 = bf2_to_f2(h[j].z);
                float2 f3 = bf2_to_f2(h[j].w);
                aA.x += v * f0.x; aA.y += v * f0.y;
                aA.z += v * f1.x; aA.w += v * f1.y;
                aB.x += v * f2.x; aB.y += v * f2.y;
                aB.z += v * f3.x; aB.w += v * f3.y;
            }
        }
        // reduce across the 4 edge-quarters (lanes q=0..3 hold partials)
#pragma unroll
        for (int m = 16; m <= 32; m <<= 1) {
            aA.x += __shfl_xor(aA.x, m); aA.y += __shfl_xor(aA.y, m);
            aA.z += __shfl_xor(aA.z, m); aA.w += __shfl_xor(aA.w, m);
            aB.x += __shfl_xor(aB.x, m); aB.y += __shfl_xor(aB.y, m);
            aB.z += __shfl_xor(aB.z, m); aB.w += __shfl_xor(aB.w, m);
        }
        if (q == 0) {
            out4[(size_t)node * 32 + 2 * ql] =
                make_float4(aA.x + bvA.x, aA.y + bvA.y,
                            aA.z + bvA.z, aA.w + bvA.w);
            out4[(size_t)node * 32 + 2 * ql + 1] =
                make_float4(aB.x + bvB.x, aB.y + bvB.y,
                            aB.z + bvB.z, aB.w + bvB.w);
        }
    }
}

// ---- K_over: drain overflow edges (adversarial skew only; exits instantly
//      when ovcnt == 0). Global float atomics over fp32 features.
__global__ __launch_bounds__(256) void k_over(
        const int4* __restrict__ ov, const int* __restrict__ ovcnt,
        const float4* __restrict__ feat4, float* __restrict__ out) {
    int total = *ovcnt;
    long long items = (long long)total * 32;
    long long stride = (long long)gridDim.x * blockDim.x;
    for (long long i = (long long)blockIdx.x * blockDim.x + threadIdx.x;
         i < items; i += stride) {
        int e = (int)(i >> 5);
        int lane = (int)(i & 31);
        int4 r = ov[e];
        float v = __int_as_float(r.z);
        float4 f = feat4[(size_t)r.x * 32 + lane];
        float* o = out + (size_t)r.y * D_FEAT + lane * 4;
        atomicAdd(o + 0, v * f.x);
        atomicAdd(o + 1, v * f.y);
        atomicAdd(o + 2, v * f.z);
        atomicAdd(o + 3, v * f.w);
    }
}

// ---------- last-resort atomic path ----------

__global__ void init_bias_kernel(float4* __restrict__ out,
                                 const float4* __restrict__ bias, int n4) {
    int i = blockIdx.x * blockDim.x + threadIdx.x;
    if (i < n4) out[i] = bias[i & (D4 - 1)];
}

__global__ void spmm_edge_kernel(const int* __restrict__ src,
                                 const int* __restrict__ dst,
                                 const float* __restrict__ vals,
                                 const float4* __restrict__ feat,
                                 float* __restrict__ out, int n_edges) {
    int tid = blockIdx.x * blockDim.x + threadIdx.x;
    int e = tid >> 5;
    int lane = tid & 31;
    if (e >= n_edges) return;
    int s = src[e];
    int d = dst[e];
    float v = vals[e];
    float4 f = feat[(size_t)s * D4 + lane];
    float* o = out + (size_t)d * D_FEAT + lane * 4;
    atomicAdd(o + 0, v * f.x);
    atomicAdd(o + 1, v * f.y);
    atomicAdd(o + 2, v * f.z);
    atomicAdd(o + 3, v * f.w);
}

extern "C" void kernel_launch(void* const* d_in, const int* in_sizes, int n_in,
                              void* d_out, int out_size, void* d_ws, size_t ws_size,
                              hipStream_t stream) {
    const int* edge_index = (const int*)d_in[0];    // (2, E) int32
    const float* edge_vals = (const float*)d_in[1]; // (E,)
    const float* features  = (const float*)d_in[2]; // (N, 128)
    const float* bias      = (const float*)d_in[3]; // (128,)

    int E = in_sizes[1];
    int N = in_sizes[2] / D_FEAT;
    const int* src = edge_index;
    const int* dst = edge_index + E;
    float* out = (float*)d_out;

    int nbkt = (N + BKT_NODES - 1) >> BKT_SHIFT;
    int n8 = N * D_FEAT / 8;        // uint4 units in the bf16 table
    int chunk = (E + NCHUNK - 1) / NCHUNK;

    // ws: fb16 | spackA[nbkt*SLOT] | ov[E] | gcur[MAXBKT] | ovcnt
    size_t fb_bytes = (size_t)N * D_FEAT * 2;
    size_t spA_bytes = (size_t)nbkt * SLOT * 8;
    size_t ov_bytes = (size_t)E * 16;
    size_t needed = fb_bytes + spA_bytes + ov_bytes + ((size_t)MAXBKT + 1) * 4;

    bool ok = (ws_size >= needed) && (N >= 1) && (N <= 65536) && (E >= 1) &&
              (E <= NCHUNK * 512 * KA_R) && (in_sizes[3] == D_FEAT) &&
              (nbkt <= MAXBKT);

    if (ok) {
        char* wp = (char*)d_ws;
        uint4* fb16 = (uint4*)wp;                      wp += fb_bytes;
        int2* spackA = (int2*)wp;                      wp += spA_bytes;
        int4* ov     = (int4*)wp;                      wp += ov_bytes;
        int* gcur    = (int*)wp;
        int* ovcnt   = gcur + MAXBKT;

        (void)hipMemsetAsync(gcur, 0, ((size_t)MAXBKT + 1) * 4, stream);

        ka_part_cvt<<<NCHUNK + 256, 512, 0, stream>>>(
            src, dst, edge_vals, E, chunk, nbkt,
            gcur, ovcnt, ov, spackA,
            (const float4*)features, fb16, n8);
        kb_sort_gather<<<nbkt, 1024, 0, stream>>>(
            gcur, spackA, (const uint4*)fb16,
            (const float4*)bias, (float4*)out, N);
        k_over<<<32, 256, 0, stream>>>(ov, ovcnt,
                                       (const float4*)features, out);
    } else {
        int no4 = out_size / 4;
        {
            int block = 256, grid = (no4 + block - 1) / block;
            init_bias_kernel<<<grid, block, 0, stream>>>((float4*)out,
                                                         (const float4*)bias, no4);
        }
        {
            int block = 256;
            long long total = (long long)E * 32;
            int grid = (int)((total + block - 1) / block);
            spmm_edge_kernel<<<grid, block, 0, stream>>>(src, dst, edge_vals,
                                                         (const float4*)features,
                                                         out, E);
        }
    }
}